// Round 2
// baseline (2593.093 us; speedup 1.0000x reference)
//
#include <hip/hip_runtime.h>
#include <cstddef>
#include <cstdint>

#define D_DIM 2048
#define S_DIM 4096
#define B_DIM 4
#define M_DIM (B_DIM * S_DIM)   // 16384
#define N1_DIM (3 * D_DIM)      // 6144

typedef short bf16x8 __attribute__((ext_vector_type(8)));
typedef float f32x4  __attribute__((ext_vector_type(4)));

typedef const unsigned int __attribute__((address_space(1))) gu32_t;
typedef unsigned int       __attribute__((address_space(3))) lu32_t;

__device__ __forceinline__ unsigned short f2bf(float f) {
    unsigned int u = __float_as_uint(f);
    u += 0x7FFFu + ((u >> 16) & 1u);   // RNE (finite inputs)
    return (unsigned short)(u >> 16);
}
__device__ __forceinline__ float bf2f(unsigned short h) {
    return __uint_as_float(((unsigned int)h) << 16);
}

// ---------- fp32 -> bf16 straight convert (8 elems/thread) ----------
__global__ void k_convert(const float* __restrict__ in, unsigned short* __restrict__ out, int n8) {
    int i = blockIdx.x * blockDim.x + threadIdx.x;
    if (i >= n8) return;
    const float4* p = (const float4*)in + (size_t)i * 2;
    float4 a = p[0];
    float4 b = p[1];
    union { unsigned short s[8]; uint4 v; } r;
    r.s[0] = f2bf(a.x); r.s[1] = f2bf(a.y); r.s[2] = f2bf(a.z); r.s[3] = f2bf(a.w);
    r.s[4] = f2bf(b.x); r.s[5] = f2bf(b.y); r.s[6] = f2bf(b.z); r.s[7] = f2bf(b.w);
    ((uint4*)out)[i] = r.v;
}

// ---------- fp32 (R x C) -> bf16 transposed (C x R), plain ----------
__global__ void k_transpose(const float* __restrict__ in, unsigned short* __restrict__ out,
                            int R, int C) {
    __shared__ float t[32][33];
    int c0 = blockIdx.x * 32, r0 = blockIdx.y * 32;
    int x = threadIdx.x;
    for (int yy = threadIdx.y; yy < 32; yy += 8)
        t[yy][x] = in[(size_t)(r0 + yy) * C + c0 + x];
    __syncthreads();
    for (int yy = threadIdx.y; yy < 32; yy += 8)
        out[(size_t)(c0 + yy) * R + r0 + x] = f2bf(t[x][yy]);
}

// ---------- W_in (K x 3D) -> Wp (3D x K) with d-tile plane interleave ----------
// Source col n (plane p = n/2048, d = n%2048) -> Wp row (d/64)*192 + p*64 + d%64
__global__ void k_transpose_wp(const float* __restrict__ in, unsigned short* __restrict__ out) {
    __shared__ float t[32][33];
    int c0 = blockIdx.x * 32, r0 = blockIdx.y * 32;
    int x = threadIdx.x;
    for (int yy = threadIdx.y; yy < 32; yy += 8)
        t[yy][x] = in[(size_t)(r0 + yy) * N1_DIM + c0 + x];
    __syncthreads();
    for (int yy = threadIdx.y; yy < 32; yy += 8) {
        const int n = c0 + yy;
        const int p = n >> 11, d = n & 2047;
        const int orow = (d >> 6) * 192 + p * 64 + (d & 63);
        out[(size_t)orow * D_DIM + r0 + x] = f2bf(t[x][yy]);
    }
}

// ---------- fused GEMM1 + gate + causal conv(L=3) ----------
// Block: 128 s-rows x 64 d-cols. Computes B_gate/C_gate/x_proj tiles (192 N-cols),
// 2-row causal halo via one extra 16-row MFMA strip, writes y bf16 directly.
__global__ __launch_bounds__(256, 2)
void k_gemm_fused(const unsigned short* __restrict__ A, const unsigned short* __restrict__ Wp,
                  const float* __restrict__ conv_w, unsigned short* __restrict__ Y) {
    __shared__ __align__(16) char smem[59392];
    unsigned short* As = (unsigned short*)smem;            // 144 rows x 64 (rows 0..15 = halo)
    unsigned short* Bs = (unsigned short*)(smem + 18432);  // 192 rows x 64
    float* BxL         = (float*)smem;                     // 130 x 65 fp32 (aliases As/Bs)
    unsigned short* yL = (unsigned short*)(smem + 43008);  // 128 x 64 bf16

    const int tid  = threadIdx.x;
    const int wave = tid >> 6;
    const int lane = tid & 63;
    const int m0  = blockIdx.y * 128;
    const int d0g = blockIdx.x * 64;
    const int wp0 = blockIdx.x * 192;

    const int srow = lane >> 3;    // staging: row within 8-row segment
    const int gd   = lane & 7;     // staging: dest granule
    const int quad = lane >> 4;
    const int rsel = lane & 15;

    f32x4 acc[2][12] = {};
    f32x4 accH1 = {}, accH2 = {};

    const int K = D_DIM;
    const int KT = K >> 6;
    for (int kt = 0; kt < KT; ++kt) {
        const int k0 = kt << 6;
        __syncthreads();
        // A: 18 segs (2 halo + 16 main), rows m0-16 .. m0+127 (clamped at 0)
        #pragma unroll
        for (int i = 0; i < 5; ++i) {
            const int seg = i * 4 + wave;          // wave-uniform guard
            if (seg < 18) {
                int rowg = m0 - 16 + seg * 8 + srow;
                if (rowg < 0) rowg = 0;            // m0==0: safe garbage, zeroed later
                const int gs = gd ^ srow;
                const unsigned short* ga = A + (size_t)rowg * K + k0 + gs * 8;
                __builtin_amdgcn_global_load_lds((gu32_t*)ga, (lu32_t*)(As + seg * 512), 16, 0, 0);
            }
        }
        // Wp: 24 segs
        #pragma unroll
        for (int i = 0; i < 6; ++i) {
            const int seg = i * 4 + wave;
            const int gs = gd ^ srow;
            const unsigned short* gb = Wp + (size_t)(wp0 + seg * 8 + srow) * K + k0 + gs * 8;
            __builtin_amdgcn_global_load_lds((gu32_t*)gb, (lu32_t*)(Bs + seg * 512), 16, 0, 0);
        }
        __syncthreads();

        #pragma unroll
        for (int kb = 0; kb < 2; ++kb) {
            const int gsw = ((kb * 4 + quad) ^ (rsel & 7)) * 8;
            bf16x8 af[2], bfr[12];
            const bf16x8 afh = *(const bf16x8*)&As[rsel * 64 + gsw];
            #pragma unroll
            for (int i = 0; i < 2; ++i)
                af[i] = *(const bf16x8*)&As[(16 + wave * 32 + i * 16 + rsel) * 64 + gsw];
            #pragma unroll
            for (int j = 0; j < 12; ++j)
                bfr[j] = *(const bf16x8*)&Bs[(j * 16 + rsel) * 64 + gsw];
            #pragma unroll
            for (int i = 0; i < 2; ++i)
                #pragma unroll
                for (int j = 0; j < 12; ++j)
                    acc[i][j] = __builtin_amdgcn_mfma_f32_16x16x32_bf16(af[i], bfr[j], acc[i][j], 0, 0, 0);
            // halo strip (rows s0-16..s0-1): wave w covers d in [16w,16w+16)
            accH1 = __builtin_amdgcn_mfma_f32_16x16x32_bf16(afh, bfr[wave],     accH1, 0, 0, 0);
            accH2 = __builtin_amdgcn_mfma_f32_16x16x32_bf16(afh, bfr[8 + wave], accH2, 0, 0, 0);
        }
    }

    // ---- epilogue ----
    __syncthreads();                    // all K-loop ds_reads done before aliasing As/Bs
    // Bx = B_gate * x_proj into LDS (rows +2 = causal pad offset), stride 65 breaks banks
    #pragma unroll
    for (int i = 0; i < 2; ++i)
        #pragma unroll
        for (int jd = 0; jd < 4; ++jd)
            #pragma unroll
            for (int r = 0; r < 4; ++r) {
                const int row = wave * 32 + i * 16 + quad * 4 + r;
                const int d   = jd * 16 + rsel;
                BxL[(row + 2) * 65 + d] = acc[i][jd][r] * acc[i][8 + jd][r];
            }
    const bool szero = ((m0 & (S_DIM - 1)) == 0);   // batch boundary: halo = 0
    if (quad == 3) {
        #pragma unroll
        for (int r = 2; r < 4; ++r) {
            const int d = wave * 16 + rsel;          // halo rows 14,15 <-> s0-2, s0-1
            BxL[(r - 2) * 65 + d] = szero ? 0.f : (accH1[r] * accH2[r]);
        }
    }
    __syncthreads();
    // y = C_gate * (w0*Bx[s-2] + w1*Bx[s-1] + w2*Bx[s])
    #pragma unroll
    for (int jd = 0; jd < 4; ++jd) {
        const int d = jd * 16 + rsel;
        const float* w = conv_w + (size_t)(d0g + d) * 3;
        const float w0 = w[0], w1 = w[1], w2 = w[2];
        #pragma unroll
        for (int i = 0; i < 2; ++i)
            #pragma unroll
            for (int r = 0; r < 4; ++r) {
                const int row = wave * 32 + i * 16 + quad * 4 + r;
                const float conv = w0 * BxL[row * 65 + d]
                                 + w1 * BxL[(row + 1) * 65 + d]
                                 + w2 * BxL[(row + 2) * 65 + d];
                yL[row * 64 + d] = f2bf(acc[i][4 + jd][r] * conv);
            }
    }
    __syncthreads();
    // coalesced store: 128 rows x 128B
    #pragma unroll
    for (int k = 0; k < 4; ++k) {
        const int u = k * 256 + tid;
        const int row = u >> 3, cg = u & 7;
        *(uint4*)&Y[(size_t)(m0 + row) * D_DIM + d0g + cg * 8] = *(const uint4*)&yL[row * 64 + cg * 8];
    }
}

// ---------- bf16 GEMM: C[M,N] = A[M,K] * Bt[N,K]^T (GEMM2, fp32 out) ----------
__global__ __launch_bounds__(256, 2)
void k_gemm2(const unsigned short* __restrict__ A, const unsigned short* __restrict__ Bt,
             float* __restrict__ Cp, int N, int K) {
    __shared__ unsigned short As[128 * 64];
    __shared__ unsigned short Bs[128 * 64];

    const int tid  = threadIdx.x;
    const int wave = tid >> 6;
    const int lane = tid & 63;
    const int m0 = blockIdx.y * 128;
    const int n0 = blockIdx.x * 128;
    const int wm = (wave & 1) * 64;
    const int wn = (wave >> 1) * 64;

    f32x4 acc[4][4] = {};

    const int srow = lane >> 3;
    const int gd   = lane & 7;
    const int quad = lane >> 4;
    const int rsel = lane & 15;

    const int KT = K >> 6;
    for (int kt = 0; kt < KT; ++kt) {
        const int k0 = kt << 6;
        __syncthreads();
        #pragma unroll
        for (int i = 0; i < 4; ++i) {
            const int seg = i * 4 + wave;
            const int row = seg * 8 + srow;
            const int gs  = gd ^ (row & 7);
            const unsigned short* ga = A  + (size_t)(m0 + row) * K + k0 + gs * 8;
            const unsigned short* gb = Bt + (size_t)(n0 + row) * K + k0 + gs * 8;
            __builtin_amdgcn_global_load_lds((gu32_t*)ga, (lu32_t*)(As + seg * 512), 16, 0, 0);
            __builtin_amdgcn_global_load_lds((gu32_t*)gb, (lu32_t*)(Bs + seg * 512), 16, 0, 0);
        }
        __syncthreads();

        #pragma unroll
        for (int kb = 0; kb < 2; ++kb) {
            bf16x8 af[4], bfr[4];
            #pragma unroll
            for (int i = 0; i < 4; ++i) {
                const int ra = wm + i * 16 + rsel;
                const int ga = (kb * 4 + quad) ^ (ra & 7);
                af[i] = *(const bf16x8*)&As[ra * 64 + ga * 8];
                const int rb = wn + i * 16 + rsel;
                const int gb = (kb * 4 + quad) ^ (rb & 7);
                bfr[i] = *(const bf16x8*)&Bs[rb * 64 + gb * 8];
            }
            #pragma unroll
            for (int i = 0; i < 4; ++i)
                #pragma unroll
                for (int j = 0; j < 4; ++j)
                    acc[i][j] = __builtin_amdgcn_mfma_f32_16x16x32_bf16(af[i], bfr[j], acc[i][j], 0, 0, 0);
        }
    }

    #pragma unroll
    for (int i = 0; i < 4; ++i)
        #pragma unroll
        for (int j = 0; j < 4; ++j) {
            const int col  = n0 + wn + j * 16 + rsel;
            const int rowb = m0 + wm + i * 16 + quad * 4;
            #pragma unroll
            for (int r = 0; r < 4; ++r)
                Cp[(size_t)(rowb + r) * N + col] = acc[i][j][r];
        }
}

extern "C" void kernel_launch(void* const* d_in, const int* in_sizes, int n_in,
                              void* d_out, int out_size, void* d_ws, size_t ws_size,
                              hipStream_t stream) {
    const float* x      = (const float*)d_in[0];   // (4,4096,2048)
    const float* W_in   = (const float*)d_in[1];   // (2048,6144)
    const float* conv_w = (const float*)d_in[2];   // (2048,3)
    const float* W_out  = (const float*)d_in[3];   // (2048,2048)
    float* out = (float*)d_out;

    // workspace: xb 64MiB | Wp 24MiB | Wt_out 8MiB | y 64MiB  (160 MiB)
    char* ws = (char*)d_ws;
    unsigned short* xb     = (unsigned short*)ws;
    unsigned short* Wp     = (unsigned short*)(ws + (size_t)67108864);
    unsigned short* Wt_out = (unsigned short*)(ws + (size_t)67108864 + 25165824);
    unsigned short* y      = (unsigned short*)(ws + (size_t)67108864 + 25165824 + 8388608);

    const int n8 = M_DIM * D_DIM / 8;
    k_convert<<<dim3((n8 + 255) / 256), 256, 0, stream>>>(x, xb, n8);
    k_transpose_wp<<<dim3(N1_DIM / 32, D_DIM / 32), dim3(32, 8), 0, stream>>>(W_in, Wp);
    k_transpose<<<dim3(D_DIM / 32, D_DIM / 32), dim3(32, 8), 0, stream>>>(W_out, Wt_out, D_DIM, D_DIM);

    k_gemm_fused<<<dim3(D_DIM / 64, M_DIM / 128), 256, 0, stream>>>(xb, Wp, conv_w, y);
    k_gemm2<<<dim3(D_DIM / 128, M_DIM / 128), 256, 0, stream>>>(y, Wt_out, out, D_DIM, D_DIM);
}

// Round 3
// 1822.969 us; speedup vs baseline: 1.4225x; 1.4225x over previous
//
#include <hip/hip_runtime.h>
#include <cstddef>
#include <cstdint>

#define D_DIM 2048
#define S_DIM 4096
#define B_DIM 4
#define M_DIM (B_DIM * S_DIM)   // 16384
#define N1_DIM (3 * D_DIM)      // 6144

typedef short bf16x8 __attribute__((ext_vector_type(8)));
typedef float f32x4  __attribute__((ext_vector_type(4)));

typedef const unsigned int __attribute__((address_space(1))) gu32_t;
typedef unsigned int       __attribute__((address_space(3))) lu32_t;

__device__ __forceinline__ unsigned short f2bf(float f) {
    unsigned int u = __float_as_uint(f);
    u += 0x7FFFu + ((u >> 16) & 1u);   // RNE (finite inputs)
    return (unsigned short)(u >> 16);
}
__device__ __forceinline__ float bf2f(unsigned short h) {
    return __uint_as_float(((unsigned int)h) << 16);
}

// ---------- fp32 -> bf16 straight convert (8 elems/thread) ----------
__global__ void k_convert(const float* __restrict__ in, unsigned short* __restrict__ out, int n8) {
    int i = blockIdx.x * blockDim.x + threadIdx.x;
    if (i >= n8) return;
    const float4* p = (const float4*)in + (size_t)i * 2;
    float4 a = p[0];
    float4 b = p[1];
    union { unsigned short s[8]; uint4 v; } r;
    r.s[0] = f2bf(a.x); r.s[1] = f2bf(a.y); r.s[2] = f2bf(a.z); r.s[3] = f2bf(a.w);
    r.s[4] = f2bf(b.x); r.s[5] = f2bf(b.y); r.s[6] = f2bf(b.z); r.s[7] = f2bf(b.w);
    ((uint4*)out)[i] = r.v;
}

// ---------- fp32 (R x C) -> bf16 transposed (C x R), plain ----------
__global__ void k_transpose(const float* __restrict__ in, unsigned short* __restrict__ out,
                            int R, int C) {
    __shared__ float t[32][33];
    int c0 = blockIdx.x * 32, r0 = blockIdx.y * 32;
    int x = threadIdx.x;
    for (int yy = threadIdx.y; yy < 32; yy += 8)
        t[yy][x] = in[(size_t)(r0 + yy) * C + c0 + x];
    __syncthreads();
    for (int yy = threadIdx.y; yy < 32; yy += 8)
        out[(size_t)(c0 + yy) * R + r0 + x] = f2bf(t[x][yy]);
}

// ---------- W_in (K x 3D) -> Wp (3D x K) with d-tile plane interleave ----------
// Source col n (plane p = n/2048, d = n%2048) -> Wp row (d/64)*192 + p*64 + d%64
__global__ void k_transpose_wp(const float* __restrict__ in, unsigned short* __restrict__ out) {
    __shared__ float t[32][33];
    int c0 = blockIdx.x * 32, r0 = blockIdx.y * 32;
    int x = threadIdx.x;
    for (int yy = threadIdx.y; yy < 32; yy += 8)
        t[yy][x] = in[(size_t)(r0 + yy) * N1_DIM + c0 + x];
    __syncthreads();
    for (int yy = threadIdx.y; yy < 32; yy += 8) {
        const int n = c0 + yy;
        const int p = n >> 11, d = n & 2047;
        const int orow = (d >> 6) * 192 + p * 64 + (d & 63);
        out[(size_t)orow * D_DIM + r0 + x] = f2bf(t[x][yy]);
    }
}

// ---------- fused GEMM1 + gate + causal conv(L=3), plane-per-wave-pair ----------
// Block: 128 s-rows x 64 d-cols (192 N-cols incl 3 planes), 6 waves.
// Wave pair p covers plane p; each wave = 64 rows x 64 cols = acc[4][4] (R1 profile).
// Halo: rows m0-16..m0-1 via one 16-row strip (B and x planes only).
__global__ __launch_bounds__(384, 3)
void k_fused(const unsigned short* __restrict__ A, const unsigned short* __restrict__ Wp,
             const float* __restrict__ conv_w, unsigned short* __restrict__ Y) {
    __shared__ __align__(16) char smem[52752];
    unsigned short* As = (unsigned short*)smem;            // 144 x 64 bf16 (rows 0..15 halo)
    unsigned short* Bs = (unsigned short*)(smem + 18432);  // 192 x 64 bf16
    float* BxL         = (float*)smem;                     // 130 x 66 f32 (alias, epilogue)
    unsigned short* yL = (unsigned short*)(smem + 34320);  // 128 x 72 bf16 (alias, epilogue)

    const int tid  = threadIdx.x;
    const int wave = tid >> 6;          // 0..5
    const int lane = tid & 63;
    const int p    = wave >> 1;         // 0:B_gate 1:C_gate 2:x_proj
    const int h    = wave & 1;
    const int wm   = h * 64;
    const int m0   = blockIdx.y * 128;
    const int d0g  = blockIdx.x * 64;
    const int wp0  = blockIdx.x * 192;

    const int srow = lane >> 3;         // staging row within 8-row segment
    const int gd   = lane & 7;          // staging dest granule
    const int quad = lane >> 4;
    const int rsel = lane & 15;

    f32x4 acc[4][4] = {};
    f32x4 accH[2] = {};

    for (int kt = 0; kt < 32; ++kt) {
        const int k0 = kt << 6;
        __syncthreads();
        // A: 18 segs = 3 iters x 6 waves (rows m0-16 .. m0+127, clamped at 0)
        #pragma unroll
        for (int i = 0; i < 3; ++i) {
            const int seg = i * 6 + wave;           // wave-uniform
            int rowg = m0 - 16 + seg * 8 + srow;
            if (rowg < 0) rowg = 0;                 // m0==0: finite garbage, zeroed later
            const int gs = gd ^ srow;
            const unsigned short* ga = A + (size_t)rowg * D_DIM + k0 + gs * 8;
            __builtin_amdgcn_global_load_lds((gu32_t*)ga, (lu32_t*)(As + seg * 512), 16, 0, 0);
        }
        // Wp: 24 segs = 4 iters x 6 waves
        #pragma unroll
        for (int i = 0; i < 4; ++i) {
            const int seg = i * 6 + wave;
            const int gs = gd ^ srow;
            const unsigned short* gb = Wp + (size_t)(wp0 + seg * 8 + srow) * D_DIM + k0 + gs * 8;
            __builtin_amdgcn_global_load_lds((gu32_t*)gb, (lu32_t*)(Bs + seg * 512), 16, 0, 0);
        }
        __syncthreads();

        #pragma unroll
        for (int kb = 0; kb < 2; ++kb) {
            const int gsw = ((kb * 4 + quad) ^ (rsel & 7)) * 8;
            const bf16x8 afh = *(const bf16x8*)&As[rsel * 64 + gsw];
            bf16x8 af[4], bfr[4];
            #pragma unroll
            for (int i = 0; i < 4; ++i)
                af[i] = *(const bf16x8*)&As[(16 + wm + i * 16 + rsel) * 64 + gsw];
            #pragma unroll
            for (int j = 0; j < 4; ++j)
                bfr[j] = *(const bf16x8*)&Bs[(p * 64 + j * 16 + rsel) * 64 + gsw];
            #pragma unroll
            for (int i = 0; i < 4; ++i)
                #pragma unroll
                for (int j = 0; j < 4; ++j)
                    acc[i][j] = __builtin_amdgcn_mfma_f32_16x16x32_bf16(af[i], bfr[j], acc[i][j], 0, 0, 0);
            if (p != 1) {   // halo needed only for B_gate / x_proj (wave-uniform branch)
                accH[0] = __builtin_amdgcn_mfma_f32_16x16x32_bf16(afh, bfr[2 * h + 0], accH[0], 0, 0, 0);
                accH[1] = __builtin_amdgcn_mfma_f32_16x16x32_bf16(afh, bfr[2 * h + 1], accH[1], 0, 0, 0);
            }
        }
    }

    // ---- epilogue: Bx exchange + conv + gate ----
    const bool szero = ((m0 & (S_DIM - 1)) == 0);   // batch boundary: halo = 0
    __syncthreads();                                 // staging LDS dead from here
    if (p == 0) {                                    // phase 1: write B_gate -> BxL (+2 row offset)
        #pragma unroll
        for (int i = 0; i < 4; ++i)
            #pragma unroll
            for (int j = 0; j < 4; ++j)
                #pragma unroll
                for (int r = 0; r < 4; ++r) {
                    const int row = wm + i * 16 + quad * 4 + r;
                    BxL[(row + 2) * 66 + j * 16 + rsel] = acc[i][j][r];
                }
        if (quad == 3) {                             // halo rows 14,15 <-> s0-2, s0-1
            #pragma unroll
            for (int jj = 0; jj < 2; ++jj)
                #pragma unroll
                for (int r = 2; r < 4; ++r)
                    BxL[(r - 2) * 66 + (2 * h + jj) * 16 + rsel] = szero ? 0.f : accH[jj][r];
        }
    }
    __syncthreads();
    if (p == 2) {                                    // phase 2: multiply in x_proj
        #pragma unroll
        for (int i = 0; i < 4; ++i)
            #pragma unroll
            for (int j = 0; j < 4; ++j)
                #pragma unroll
                for (int r = 0; r < 4; ++r) {
                    const int row = wm + i * 16 + quad * 4 + r;
                    BxL[(row + 2) * 66 + j * 16 + rsel] *= acc[i][j][r];
                }
        if (quad == 3) {
            #pragma unroll
            for (int jj = 0; jj < 2; ++jj)
                #pragma unroll
                for (int r = 2; r < 4; ++r)
                    BxL[(r - 2) * 66 + (2 * h + jj) * 16 + rsel] *= accH[jj][r];
        }
    }
    __syncthreads();
    if (p == 1) {                                    // phase 3: y = C_gate * conv(Bx)
        #pragma unroll
        for (int j = 0; j < 4; ++j) {
            const int col = j * 16 + rsel;
            const float* w = conv_w + (size_t)(d0g + col) * 3;
            const float w0 = w[0], w1 = w[1], w2 = w[2];
            #pragma unroll
            for (int i = 0; i < 4; ++i)
                #pragma unroll
                for (int r = 0; r < 4; ++r) {
                    const int row = wm + i * 16 + quad * 4 + r;
                    const float conv = w0 * BxL[row * 66 + col]
                                     + w1 * BxL[(row + 1) * 66 + col]
                                     + w2 * BxL[(row + 2) * 66 + col];
                    yL[row * 72 + col] = f2bf(acc[i][j][r] * conv);
                }
        }
    }
    __syncthreads();
    // coalesced flush: 1024 uint4
    #pragma unroll
    for (int k = 0; k < 3; ++k) {
        const int u = k * 384 + tid;
        if (u < 1024) {
            const int row = u >> 3, cg = u & 7;
            *(uint4*)&Y[(size_t)(m0 + row) * D_DIM + d0g + cg * 8] = *(const uint4*)&yL[row * 72 + cg * 8];
        }
    }
}

// ---------- bf16 GEMM: C[M,N] = A[M,K] * Bt[N,K]^T (GEMM2, fp32 out) ----------
__global__ __launch_bounds__(256, 2)
void k_gemm2(const unsigned short* __restrict__ A, const unsigned short* __restrict__ Bt,
             float* __restrict__ Cp, int N, int K) {
    __shared__ unsigned short As[128 * 64];
    __shared__ unsigned short Bs[128 * 64];

    const int tid  = threadIdx.x;
    const int wave = tid >> 6;
    const int lane = tid & 63;
    const int m0 = blockIdx.y * 128;
    const int n0 = blockIdx.x * 128;
    const int wm = (wave & 1) * 64;
    const int wn = (wave >> 1) * 64;

    f32x4 acc[4][4] = {};

    const int srow = lane >> 3;
    const int gd   = lane & 7;
    const int quad = lane >> 4;
    const int rsel = lane & 15;

    const int KT = K >> 6;
    for (int kt = 0; kt < KT; ++kt) {
        const int k0 = kt << 6;
        __syncthreads();
        #pragma unroll
        for (int i = 0; i < 4; ++i) {
            const int seg = i * 4 + wave;
            const int row = seg * 8 + srow;
            const int gs  = gd ^ (row & 7);
            const unsigned short* ga = A  + (size_t)(m0 + row) * K + k0 + gs * 8;
            const unsigned short* gb = Bt + (size_t)(n0 + row) * K + k0 + gs * 8;
            __builtin_amdgcn_global_load_lds((gu32_t*)ga, (lu32_t*)(As + seg * 512), 16, 0, 0);
            __builtin_amdgcn_global_load_lds((gu32_t*)gb, (lu32_t*)(Bs + seg * 512), 16, 0, 0);
        }
        __syncthreads();

        #pragma unroll
        for (int kb = 0; kb < 2; ++kb) {
            bf16x8 af[4], bfr[4];
            #pragma unroll
            for (int i = 0; i < 4; ++i) {
                const int ra = wm + i * 16 + rsel;
                const int ga = (kb * 4 + quad) ^ (ra & 7);
                af[i] = *(const bf16x8*)&As[ra * 64 + ga * 8];
                const int rb = wn + i * 16 + rsel;
                const int gb = (kb * 4 + quad) ^ (rb & 7);
                bfr[i] = *(const bf16x8*)&Bs[rb * 64 + gb * 8];
            }
            #pragma unroll
            for (int i = 0; i < 4; ++i)
                #pragma unroll
                for (int j = 0; j < 4; ++j)
                    acc[i][j] = __builtin_amdgcn_mfma_f32_16x16x32_bf16(af[i], bfr[j], acc[i][j], 0, 0, 0);
        }
    }

    #pragma unroll
    for (int i = 0; i < 4; ++i)
        #pragma unroll
        for (int j = 0; j < 4; ++j) {
            const int col  = n0 + wn + j * 16 + rsel;
            const int rowb = m0 + wm + i * 16 + quad * 4;
            #pragma unroll
            for (int r = 0; r < 4; ++r)
                Cp[(size_t)(rowb + r) * N + col] = acc[i][j][r];
        }
}

extern "C" void kernel_launch(void* const* d_in, const int* in_sizes, int n_in,
                              void* d_out, int out_size, void* d_ws, size_t ws_size,
                              hipStream_t stream) {
    const float* x      = (const float*)d_in[0];   // (4,4096,2048)
    const float* W_in   = (const float*)d_in[1];   // (2048,6144)
    const float* conv_w = (const float*)d_in[2];   // (2048,3)
    const float* W_out  = (const float*)d_in[3];   // (2048,2048)
    float* out = (float*)d_out;

    // workspace: xb 64MiB | Wp 24MiB | Wt_out 8MiB | y 64MiB  (160 MiB)
    char* ws = (char*)d_ws;
    unsigned short* xb     = (unsigned short*)ws;
    unsigned short* Wp     = (unsigned short*)(ws + (size_t)67108864);
    unsigned short* Wt_out = (unsigned short*)(ws + (size_t)67108864 + 25165824);
    unsigned short* y      = (unsigned short*)(ws + (size_t)67108864 + 25165824 + 8388608);

    const int n8 = M_DIM * D_DIM / 8;
    k_convert<<<dim3((n8 + 255) / 256), 256, 0, stream>>>(x, xb, n8);
    k_transpose_wp<<<dim3(N1_DIM / 32, D_DIM / 32), dim3(32, 8), 0, stream>>>(W_in, Wp);
    k_transpose<<<dim3(D_DIM / 32, D_DIM / 32), dim3(32, 8), 0, stream>>>(W_out, Wt_out, D_DIM, D_DIM);

    k_fused<<<dim3(D_DIM / 64, M_DIM / 128), 384, 0, stream>>>(xb, Wp, conv_w, y);
    k_gemm2<<<dim3(D_DIM / 128, M_DIM / 128), 256, 0, stream>>>(y, Wt_out, out, D_DIM, D_DIM);
}